// Round 4
// baseline (285.621 us; speedup 1.0000x reference)
//
#include <hip/hip_runtime.h>
#include <hip/hip_bf16.h>

typedef __bf16 v8bf __attribute__((ext_vector_type(8)));
typedef __bf16 v4bf __attribute__((ext_vector_type(4)));
typedef float  f32x4 __attribute__((ext_vector_type(4)));

#define NTOK 1024
#define HDIM 1024
#define FDIM 3584
#define NEXP 8
#define NPAIR 2048
#define MAXT1 24
#define MAXT2 40
#define LDP 40   // padded LDS row stride (bf16 elems): 80 B -> conflict-free-ish

// workspace layout (bytes)
#define OFF_COUNTS   0
#define OFF_OFFSETS  64
#define OFF_NT1      128
#define OFF_NT2      132
#define OFF_T1E      192
#define OFF_T1M      320
#define OFF_T2E      448
#define OFF_T2M      640
#define OFF_TOKIDX   1024
#define OFF_TOKWT    (1024 + 4*NPAIR)
#define OFF_PAIRTOK  (OFF_TOKWT + 4*NPAIR)
#define OFF_PAIRWT   (OFF_PAIRTOK + 4*NPAIR)
#define OFF_SLOTOF   (OFF_PAIRWT + 4*NPAIR)
#define OFF_XB       65536                          // bf16 [1024][1024] = 2 MB
#define OFF_ACT      (OFF_XB + 2ull*NTOK*HDIM)      // bf16 [2048][3584]
#define OFF_Y        (OFF_ACT + 2ull*NPAIR*FDIM)    // f32  [2048][1024]

static __device__ inline v4bf cvt4(float4 f) {
    v4bf r;
    r[0] = (__bf16)f.x; r[1] = (__bf16)f.y; r[2] = (__bf16)f.z; r[3] = (__bf16)f.w;
    return r;
}

#define BAR() do { asm volatile("s_waitcnt lgkmcnt(0)" ::: "memory"); \
                   __builtin_amdgcn_s_barrier(); } while (0)

// ---------------- x -> bf16 ----------------
__global__ __launch_bounds__(256) void moe_cvtx(const float* __restrict__ x,
                                                __bf16* __restrict__ xb)
{
    const size_t i = ((size_t)blockIdx.x * 256 + threadIdx.x) * 4;
    float4 v = *(const float4*)(x + i);
    *(v4bf*)(xb + i) = cvt4(v);
}

// ---------------- router ----------------
__global__ __launch_bounds__(256) void moe_router(
    const float* __restrict__ x, const float* __restrict__ gw,
    float* __restrict__ logits, int* __restrict__ counts,
    int* __restrict__ tok_idx, float* __restrict__ tok_wt)
{
    const int lane = threadIdx.x & 63;
    const int wv = threadIdx.x >> 6;
    const int t = blockIdx.x * 4 + wv;
    const float* xr = x + (size_t)t * HDIM;

    float acc[NEXP];
#pragma unroll
    for (int e = 0; e < NEXP; ++e) acc[e] = 0.f;
#pragma unroll
    for (int j = 0; j < 4; ++j) {
        int h = lane * 4 + j * 256;
        float4 xv = *(const float4*)(xr + h);
#pragma unroll
        for (int e = 0; e < NEXP; ++e) {
            float4 g = *(const float4*)(gw + e * HDIM + h);
            acc[e] += xv.x * g.x + xv.y * g.y + xv.z * g.z + xv.w * g.w;
        }
    }
#pragma unroll
    for (int e = 0; e < NEXP; ++e) {
#pragma unroll
        for (int s = 32; s > 0; s >>= 1) acc[e] += __shfl_xor(acc[e], s);
    }
    if (lane == 0) {
#pragma unroll
        for (int e = 0; e < NEXP; ++e) logits[t * NEXP + e] = acc[e];
        int i0 = 0;
#pragma unroll
        for (int e = 1; e < NEXP; ++e) if (acc[e] > acc[i0]) i0 = e;
        int i1 = (i0 == 0) ? 1 : 0;
#pragma unroll
        for (int e = 0; e < NEXP; ++e) if (e != i0 && acc[e] > acc[i1]) i1 = e;
        float w0 = 1.f / (1.f + expf(acc[i1] - acc[i0]));
        float w1 = 1.f - w0;
        tok_idx[2 * t] = i0; tok_idx[2 * t + 1] = i1;
        tok_wt[2 * t] = w0;  tok_wt[2 * t + 1] = w1;
        atomicAdd(&counts[i0], 1);
        atomicAdd(&counts[i1], 1);
    }
}

// ---------------- scatter + tile lists ----------------
__global__ void moe_scatter(const int* __restrict__ counts, const int* __restrict__ tok_idx,
                            const float* __restrict__ tok_wt, int* __restrict__ offsets,
                            int* __restrict__ pair_token, float* __restrict__ pair_wt,
                            int* __restrict__ slot_of,
                            int* __restrict__ t1e, int* __restrict__ t1m, int* __restrict__ nt1,
                            int* __restrict__ t2e, int* __restrict__ t2m, int* __restrict__ nt2)
{
    __shared__ int cur[NEXP];
    const int tid = threadIdx.x;
    if (tid == 0) {
        int run = 0, n1 = 0, n2 = 0;
        for (int e = 0; e < NEXP; ++e) {
            offsets[e] = run; cur[e] = run;
            for (int m0 = 0; m0 < counts[e]; m0 += 128) { t1e[n1] = e; t1m[n1] = m0; ++n1; }
            for (int m0 = 0; m0 < counts[e]; m0 += 64)  { t2e[n2] = e; t2m[n2] = m0; ++n2; }
            run += counts[e];
        }
        *nt1 = n1; *nt2 = n2;
    }
    __syncthreads();
    for (int p = tid; p < 2 * NTOK; p += blockDim.x) {
        int e = tok_idx[p];
        int s = atomicAdd(&cur[e], 1);
        pair_token[s] = p >> 1;
        pair_wt[s] = tok_wt[p];
        slot_of[p] = s;
    }
}

// ---------------- GEMM1: act = silu(X@w1^T)*(X@w3^T); BM=128 BN=64 BK=32, 2-deep ----------------
__global__ __launch_bounds__(256, 3) void moe_gemm1(
    const __bf16* __restrict__ xb, const float* __restrict__ w1g,
    const float* __restrict__ w3g, const int* __restrict__ counts,
    const int* __restrict__ offsets, const int* __restrict__ pair_token,
    const int* __restrict__ t1e, const int* __restrict__ t1m,
    const int* __restrict__ nt1,
    __bf16* __restrict__ act)
{
    const int ty = blockIdx.y;
    if (ty >= *nt1) return;
    const int e = t1e[ty];
    const int m0 = t1m[ty];
    const int Me = counts[e];
    const int rows = min(128, Me - m0);
    const int slot0 = offsets[e] + m0;
    const int n0 = blockIdx.x * 64;

    __shared__ __align__(16) __bf16 As[2][128 * LDP];
    __shared__ __align__(16) __bf16 B1s[2][64 * LDP];
    __shared__ __align__(16) __bf16 B3s[2][64 * LDP];

    const int tid = threadIdx.x;
    const int lane = tid & 63;
    const int wv = tid >> 6;
    const int wm = (wv >> 1) * 64;   // 2x2 waves, wave tile 64x32
    const int wn = (wv & 1) * 32;
    const int lr = lane & 15;
    const int lk = (lane >> 4) * 8;

    f32x4 acc1[4][2], acc3[4][2];
#pragma unroll
    for (int i = 0; i < 4; ++i)
#pragma unroll
        for (int j = 0; j < 2; ++j) {
            acc1[i][j] = (f32x4){0.f, 0.f, 0.f, 0.f};
            acc3[i][j] = (f32x4){0.f, 0.f, 0.f, 0.f};
        }

    const ptrdiff_t d31 = w3g - w1g;
    // A: 128x32 bf16 per buf = 512 x 16B chunks, 2/thread
    const __bf16* aptr[2];
    int awof[2];
#pragma unroll
    for (int i = 0; i < 2; ++i) {
        int slot = tid + i * 256;
        int r = slot >> 2;
        int c = (slot & 3) * 8;
        int rr = (r < rows) ? r : 0;
        aptr[i] = xb + (size_t)pair_token[slot0 + rr] * HDIM + c;
        awof[i] = r * LDP + c;
    }
    // B: 64x32 f32 per buf, 512 float4 slots, 2/thread
    const float* bp[2];
    int bwof[2];
#pragma unroll
    for (int i = 0; i < 2; ++i) {
        int slot = tid + i * 256;
        int r = slot >> 3;
        int c = (slot & 7) * 4;
        bp[i]   = w1g + ((size_t)e * FDIM + n0 + r) * HDIM + c;
        bwof[i] = r * LDP + c;
    }

    v8bf a0[2], a1[2];
    float4 b10[2], b30[2], b11[2], b31[2];

#define LD1(AV, B1V, B3V, K0) do { _Pragma("unroll") \
    for (int i = 0; i < 2; ++i) { AV[i] = *(const v8bf*)(aptr[i] + (K0)); \
                                  B1V[i] = *(const float4*)(bp[i] + (K0)); \
                                  B3V[i] = *(const float4*)(bp[i] + d31 + (K0)); } } while (0)

#define ST1(BUF, AV, B1V, B3V) do { _Pragma("unroll") \
    for (int i = 0; i < 2; ++i) { *(v8bf*)&As[BUF][awof[i]] = AV[i]; \
                                  *(v4bf*)&B1s[BUF][bwof[i]] = cvt4(B1V[i]); \
                                  *(v4bf*)&B3s[BUF][bwof[i]] = cvt4(B3V[i]); } } while (0)

#define CMP1(BUF) do { v8bf af[4], b1f[2], b3f[2]; _Pragma("unroll") \
    for (int i = 0; i < 4; ++i) af[i] = *(const v8bf*)&As[BUF][(wm + i * 16 + lr) * LDP + lk]; \
    _Pragma("unroll") \
    for (int i = 0; i < 2; ++i) { b1f[i] = *(const v8bf*)&B1s[BUF][(wn + i * 16 + lr) * LDP + lk]; \
                                  b3f[i] = *(const v8bf*)&B3s[BUF][(wn + i * 16 + lr) * LDP + lk]; } \
    _Pragma("unroll") \
    for (int mi = 0; mi < 4; ++mi) { _Pragma("unroll") \
        for (int ni = 0; ni < 2; ++ni) { \
            acc1[mi][ni] = __builtin_amdgcn_mfma_f32_16x16x32_bf16(af[mi], b1f[ni], acc1[mi][ni], 0, 0, 0); \
            acc3[mi][ni] = __builtin_amdgcn_mfma_f32_16x16x32_bf16(af[mi], b3f[ni], acc3[mi][ni], 0, 0, 0); } } } while (0)

    LD1(a0, b10, b30, 0);
    LD1(a1, b11, b31, 32);
    for (int k0 = 0; k0 < HDIM; k0 += 64) {
        ST1(0, a0, b10, b30);
        if (k0 + 64 < HDIM) LD1(a0, b10, b30, k0 + 64);
        BAR();
        CMP1(0);
        ST1(1, a1, b11, b31);
        if (k0 + 96 < HDIM) LD1(a1, b11, b31, k0 + 96);
        BAR();
        CMP1(1);
    }
#undef LD1
#undef ST1
#undef CMP1

    const int rj = (lane >> 4) * 4;
#pragma unroll
    for (int mi = 0; mi < 4; ++mi) {
#pragma unroll
        for (int j = 0; j < 4; ++j) {
            int rm = wm + mi * 16 + rj + j;
            if (rm < rows) {
                size_t rowoff = (size_t)(slot0 + rm) * FDIM + n0 + wn;
#pragma unroll
                for (int ni = 0; ni < 2; ++ni) {
                    float h1 = acc1[mi][ni][j];
                    float h3 = acc3[mi][ni][j];
                    float sv = (h1 / (1.f + __expf(-h1))) * h3;
                    act[rowoff + ni * 16 + lr] = (__bf16)sv;
                }
            }
        }
    }
}

// ---------------- GEMM2: y = act @ w2^T; BM=64 BN=64 BK=32, 2-deep ----------------
__global__ __launch_bounds__(256, 6) void moe_gemm2(
    const __bf16* __restrict__ act, const float* __restrict__ w2g,
    const int* __restrict__ counts, const int* __restrict__ offsets,
    const int* __restrict__ t2e, const int* __restrict__ t2m,
    const int* __restrict__ nt2,
    float* __restrict__ y)
{
    const int ty = blockIdx.y;
    if (ty >= *nt2) return;
    const int e = t2e[ty];
    const int m0 = t2m[ty];
    const int Me = counts[e];
    const int rows = min(64, Me - m0);
    const int slot0 = offsets[e] + m0;
    const int n0 = blockIdx.x * 64;

    __shared__ __align__(16) __bf16 As[2][64 * LDP];
    __shared__ __align__(16) __bf16 Bs[2][64 * LDP];

    const int tid = threadIdx.x;
    const int lane = tid & 63;
    const int wv = tid >> 6;
    const int wm = (wv >> 1) * 32;
    const int wn = (wv & 1) * 32;
    const int lr = lane & 15;
    const int lk = (lane >> 4) * 8;

    f32x4 acc[2][2];
#pragma unroll
    for (int i = 0; i < 2; ++i)
#pragma unroll
        for (int j = 0; j < 2; ++j) acc[i][j] = (f32x4){0.f, 0.f, 0.f, 0.f};

    const __bf16* ap;
    int awof;
    {
        int r = tid >> 2;
        int c = (tid & 3) * 8;
        int rr = (r < rows) ? r : 0;
        ap   = act + (size_t)(slot0 + rr) * FDIM + c;
        awof = r * LDP + c;
    }
    const float* bp[2];
    int bwof[2];
#pragma unroll
    for (int i = 0; i < 2; ++i) {
        int slot = tid + i * 256;
        int r = slot >> 3;
        int c = (slot & 7) * 4;
        bp[i]   = w2g + ((size_t)e * HDIM + n0 + r) * FDIM + c;
        bwof[i] = r * LDP + c;
    }

    v8bf a8_0, a8_1;
    float4 bv0[2], bv1[2];

#define LD2(A8, BV, K0) do { A8 = *(const v8bf*)(ap + (K0)); _Pragma("unroll") \
    for (int i = 0; i < 2; ++i) BV[i] = *(const float4*)(bp[i] + (K0)); } while (0)

#define ST2(BUF, A8, BV) do { *(v8bf*)&As[BUF][awof] = A8; _Pragma("unroll") \
    for (int i = 0; i < 2; ++i) *(v4bf*)&Bs[BUF][bwof[i]] = cvt4(BV[i]); } while (0)

#define CMP2(BUF) do { v8bf af[2], bf[2]; _Pragma("unroll") \
    for (int i = 0; i < 2; ++i) { af[i] = *(const v8bf*)&As[BUF][(wm + i * 16 + lr) * LDP + lk]; \
                                  bf[i] = *(const v8bf*)&Bs[BUF][(wn + i * 16 + lr) * LDP + lk]; } \
    _Pragma("unroll") \
    for (int mi = 0; mi < 2; ++mi) { _Pragma("unroll") \
        for (int ni = 0; ni < 2; ++ni) \
            acc[mi][ni] = __builtin_amdgcn_mfma_f32_16x16x32_bf16(af[mi], bf[ni], acc[mi][ni], 0, 0, 0); } } while (0)

    LD2(a8_0, bv0, 0);
    LD2(a8_1, bv1, 32);
    for (int k0 = 0; k0 < FDIM; k0 += 64) {
        ST2(0, a8_0, bv0);
        if (k0 + 64 < FDIM) LD2(a8_0, bv0, k0 + 64);
        BAR();
        CMP2(0);
        ST2(1, a8_1, bv1);
        if (k0 + 96 < FDIM) LD2(a8_1, bv1, k0 + 96);
        BAR();
        CMP2(1);
    }
#undef LD2
#undef ST2
#undef CMP2

    const int rj = (lane >> 4) * 4;
#pragma unroll
    for (int mi = 0; mi < 2; ++mi) {
#pragma unroll
        for (int j = 0; j < 4; ++j) {
            int rm = wm + mi * 16 + rj + j;
            if (rm < rows) {
                size_t rowoff = (size_t)(slot0 + rm) * HDIM + n0 + wn;
#pragma unroll
                for (int ni = 0; ni < 2; ++ni)
                    y[rowoff + ni * 16 + lr] = acc[mi][ni][j];
            }
        }
    }
}

// ---------------- combine ----------------
__global__ __launch_bounds__(256) void moe_combine(
    const float* __restrict__ y, const int* __restrict__ slot_of,
    const float* __restrict__ pair_wt, float* __restrict__ out)
{
    const int t = blockIdx.x;
    const int tid = threadIdx.x;
    const int s0 = slot_of[2 * t];
    const int s1 = slot_of[2 * t + 1];
    const float w0 = pair_wt[s0];
    const float w1 = pair_wt[s1];
    const float4 a = *(const float4*)(y + (size_t)s0 * HDIM + tid * 4);
    const float4 b = *(const float4*)(y + (size_t)s1 * HDIM + tid * 4);
    float4 o;
    o.x = w0 * a.x + w1 * b.x;
    o.y = w0 * a.y + w1 * b.y;
    o.z = w0 * a.z + w1 * b.z;
    o.w = w0 * a.w + w1 * b.w;
    *(float4*)(out + (size_t)t * HDIM + tid * 4) = o;
}

extern "C" void kernel_launch(void* const* d_in, const int* in_sizes, int n_in,
                              void* d_out, int out_size, void* d_ws, size_t ws_size,
                              hipStream_t stream) {
    const float* x   = (const float*)d_in[0];
    const float* gw  = (const float*)d_in[1];
    const float* w1  = (const float*)d_in[2];
    const float* w2  = (const float*)d_in[3];
    const float* w3  = (const float*)d_in[4];

    float* out    = (float*)d_out;
    float* logits = out + (size_t)NTOK * HDIM;

    char* ws = (char*)d_ws;
    int*    counts     = (int*)(ws + OFF_COUNTS);
    int*    offsets    = (int*)(ws + OFF_OFFSETS);
    int*    nt1        = (int*)(ws + OFF_NT1);
    int*    nt2        = (int*)(ws + OFF_NT2);
    int*    t1e        = (int*)(ws + OFF_T1E);
    int*    t1m        = (int*)(ws + OFF_T1M);
    int*    t2e        = (int*)(ws + OFF_T2E);
    int*    t2m        = (int*)(ws + OFF_T2M);
    int*    tok_idx    = (int*)(ws + OFF_TOKIDX);
    float*  tok_wt     = (float*)(ws + OFF_TOKWT);
    int*    pair_token = (int*)(ws + OFF_PAIRTOK);
    float*  pair_wt    = (float*)(ws + OFF_PAIRWT);
    int*    slot_of    = (int*)(ws + OFF_SLOTOF);
    __bf16* xb         = (__bf16*)(ws + OFF_XB);
    __bf16* act        = (__bf16*)(ws + OFF_ACT);
    float*  yb         = (float*)(ws + OFF_Y);

    hipMemsetAsync(counts, 0, 64, stream);

    moe_cvtx<<<dim3(NTOK * HDIM / 1024), dim3(256), 0, stream>>>(x, xb);
    moe_router<<<dim3(NTOK / 4), dim3(256), 0, stream>>>(x, gw, logits, counts, tok_idx, tok_wt);
    moe_scatter<<<dim3(1), dim3(256), 0, stream>>>(counts, tok_idx, tok_wt, offsets,
                                                   pair_token, pair_wt, slot_of,
                                                   t1e, t1m, nt1, t2e, t2m, nt2);
    moe_gemm1<<<dim3(FDIM / 64, MAXT1), dim3(256), 0, stream>>>(
        xb, w1, w3, counts, offsets, pair_token, t1e, t1m, nt1, act);
    moe_gemm2<<<dim3(HDIM / 64, MAXT2), dim3(256), 0, stream>>>(
        act, w2, counts, offsets, t2e, t2m, nt2, yb);
    moe_combine<<<dim3(NTOK), dim3(256), 0, stream>>>(yb, slot_of, pair_wt, out);
}